// Round 1
// 358.116 us; speedup vs baseline: 1.0179x; 1.0179x over previous
//
#include <hip/hip_runtime.h>
#include <hip/hip_bf16.h>
#include <math.h>

#define HID 128

typedef __bf16 bf16x8 __attribute__((ext_vector_type(8)));
typedef float f32x4 __attribute__((ext_vector_type(4)));
typedef float nf4 __attribute__((ext_vector_type(4)));
typedef float v2f __attribute__((ext_vector_type(2)));
union BF8 { uint4 u; bf16x8 v; unsigned short s[8]; };

struct __attribute__((packed, aligned(4))) U3 { unsigned a, b, c; };

__device__ __forceinline__ unsigned short f2bf(float x) {
  unsigned u = __float_as_uint(x);
  unsigned r = u + 0x7FFFu + ((u >> 16) & 1u);   // RNE (finite inputs)
  return (unsigned short)(r >> 16);
}
__device__ __forceinline__ float bf2f(unsigned short h) {
  return __uint_as_float(((unsigned)h) << 16);
}
__device__ __forceinline__ void ld2bf(const unsigned short* p, float& x, float& y) {
  unsigned v = *(const unsigned*)p;
  x = __uint_as_float((v & 0xFFFFu) << 16);
  y = __uint_as_float(v & 0xFFFF0000u);
}
__device__ __forceinline__ v2f bfpair(unsigned w) {
  v2f r;
  r.x = __uint_as_float(w << 16);
  r.y = __uint_as_float(w & 0xFFFF0000u);
  return r;
}

// ================= K1: prep (blocks 0..577) + hist (blocks 578..) =================
__global__ __launch_bounds__(256) void k1_prep_hist(
    const float* __restrict__ fc_W, const float* __restrict__ Wl,
    const float* __restrict__ Wr, const float* __restrict__ We,
    const float* __restrict__ Wpost, const float* __restrict__ W1,
    const float* __restrict__ W2, const float* __restrict__ bl,
    const float* __restrict__ br, const float* __restrict__ gat_bias,
    const float* __restrict__ bpost,
    unsigned short* __restrict__ fcTh, unsigned short* __restrict__ fcTl,
    unsigned short* __restrict__ WnTh, unsigned short* __restrict__ WnTl,
    unsigned short* __restrict__ WpT, unsigned short* __restrict__ W1T,
    unsigned short* __restrict__ W2T,
    float* __restrict__ bxy, float* __restrict__ bpost2,
    const int* __restrict__ edst, int* __restrict__ count, int E) {
  int bid = blockIdx.x;
  if (bid >= 578) {                        // ---- histogram part ----
    int e = (bid - 578) * 256 + threadIdx.x;
    if (e < E) atomicAdd(&count[edst[e]], 1);
    return;
  }
  int gid = bid * 256 + threadIdx.x;
  if (gid < 32768) {                       // fc_W [128x256] -> fcT hi/lo [256][128]
    int n = gid >> 7, k = gid & 127;
    float x = fc_W[k * 256 + n];
    unsigned short h = f2bf(x);
    fcTh[n * 128 + k] = h;
    fcTl[n * 128 + k] = f2bf(x - bf2f(h));
  } else if (gid < 98304) {                // WnT [512][128] cols=[Wl|Wr|WeA|WeB]
    int i = gid - 32768; int n = i >> 7, k = i & 127;
    float x;
    if (n < 128)      x = Wl[k * 128 + n];
    else if (n < 256) x = Wr[k * 128 + (n - 128)];
    else if (n < 384) x = We[k * 128 + (n - 256)];
    else              x = We[(128 + k) * 128 + (n - 384)];
    unsigned short h = f2bf(x);
    WnTh[n * 128 + k] = h;
    if (n >= 256) WnTl[(n - 256) * 128 + k] = f2bf(x - bf2f(h));
  } else if (gid < 147456) {               // Wpost/W1/W2 -> T [128][128]
    int i = gid - 98304; int which = i >> 14; int j = i & 16383;
    int n = j >> 7, k = j & 127;
    const float* W = (which == 0) ? Wpost : (which == 1) ? W1 : W2;
    unsigned short* T = (which == 0) ? WpT : (which == 1) ? W1T : W2T;
    T[n * 128 + k] = f2bf(W[k * 128 + n]);
  } else if (gid < 147712) {               // bxy = [bl|br]
    int j = gid - 147456;
    bxy[j] = (j < 128) ? bl[j] : br[j - 128];
  } else if (gid < 147840) {               // bpost2 = bpost + gat_bias @ Wpost
    int t = gid - 147712;
    float s = bpost[t];
    for (int k = 0; k < 128; ++k) s += gat_bias[k] * Wpost[k * 128 + t];
    bpost2[t] = s;
  }
}

// ================= K2: style GEMM (blocks 0..511) + scan (block 512) =================
// style = t_emb @ fc_W + fc_b [N x 256], split hi/lo precision.
__global__ __launch_bounds__(256) void k2_style_scan(
    const float* __restrict__ A, const unsigned short* __restrict__ WTh,
    const unsigned short* __restrict__ WTl, const float* __restrict__ bias,
    float* __restrict__ C,
    const int* __restrict__ count, int* __restrict__ rowptr,
    int* __restrict__ cursor, int N, int E) {
  if (blockIdx.x == 512) {                 // ---- scan part (2-pass, 256 thr) ----
    __shared__ int wtot[4];
    int t = threadIdx.x, lane = t & 63, wv = t >> 6;
    const int4* c4 = (const int4*)count;
    int base = t * 32;
    int s = 0;
    for (int i = 0; i < 32; ++i) {
      int4 c = c4[base + i];
      s += c.x + c.y + c.z + c.w;
    }
    int incl = s;
#pragma unroll
    for (int off = 1; off < 64; off <<= 1) {
      int v = __shfl_up(incl, off);
      if (lane >= off) incl += v;
    }
    if (lane == 63) wtot[wv] = incl;
    __syncthreads();
    if (t == 0) {
      int a0 = wtot[0], a1 = wtot[1], a2 = wtot[2];
      wtot[0] = 0; wtot[1] = a0; wtot[2] = a0 + a1; wtot[3] = a0 + a1 + a2;
    }
    __syncthreads();
    int run = wtot[wv] + incl - s;
    for (int i = 0; i < 32; ++i) {
      int4 c = c4[base + i];
      int4 r;
      r.x = run; run += c.x;
      r.y = run; run += c.y;
      r.z = run; run += c.z;
      r.w = run; run += c.w;
      ((int4*)rowptr)[base + i] = r;
      ((int4*)cursor)[base + i] = r;
    }
    if (t == 255) rowptr[N] = E;
    return;
  }
  // ---- style GEMM part ----
  int tid = threadIdx.x;
  int wave = tid >> 6, lane = tid & 63;
  int m = lane & 15, q = lane >> 4;
  int r0 = blockIdx.x * 64 + wave * 16;
  const float* arow = A + (size_t)(r0 + m) * 128 + q * 8;
  BF8 Ah[4], Al[4];
#pragma unroll
  for (int kc = 0; kc < 4; ++kc) {
    float4 x0 = *(const float4*)(arow + kc * 32);
    float4 x1 = *(const float4*)(arow + kc * 32 + 4);
    float xs[8] = {x0.x, x0.y, x0.z, x0.w, x1.x, x1.y, x1.z, x1.w};
#pragma unroll
    for (int j = 0; j < 8; ++j) {
      unsigned short h = f2bf(xs[j]);
      Ah[kc].s[j] = h;
      Al[kc].s[j] = f2bf(xs[j] - bf2f(h));
    }
  }
  for (int nt = 0; nt < 16; ++nt) {
    const unsigned short* wr  = WTh + (size_t)(nt * 16 + m) * 128 + q * 8;
    const unsigned short* wrl = WTl + (size_t)(nt * 16 + m) * 128 + q * 8;
    f32x4 acc = {0.f, 0.f, 0.f, 0.f};
#pragma unroll
    for (int kc = 0; kc < 4; ++kc) {
      BF8 bh, blo;
      bh.u  = *(const uint4*)(wr + kc * 32);
      blo.u = *(const uint4*)(wrl + kc * 32);
      acc = __builtin_amdgcn_mfma_f32_16x16x32_bf16(Ah[kc].v, bh.v, acc, 0, 0, 0);
      acc = __builtin_amdgcn_mfma_f32_16x16x32_bf16(Al[kc].v, bh.v, acc, 0, 0, 0);
      acc = __builtin_amdgcn_mfma_f32_16x16x32_bf16(Ah[kc].v, blo.v, acc, 0, 0, 0);
    }
    int n = nt * 16 + m;
    float bv = bias[n];
#pragma unroll
    for (int i = 0; i < 4; ++i) {
      int row = r0 + q * 4 + i;
      C[(size_t)row * 256 + n] = acc[i] + bv;
    }
  }
}

// ================= K3: nodeP (blocks 0..255) + scatter (blocks 256..) =================
// packed row layout (interleaved for dwordx3 in k_edge): for channel pair c=0..63,
// ushort idx 6c..6c+5 = [xl_{2c}, xl_{2c+1}, A_{2c}, A_{2c+1}, B_{2c}, B_{2c+1}]
__global__ __launch_bounds__(256) void k3_node_scatter(
    const float* __restrict__ h_source, const float* __restrict__ style,
    const float* __restrict__ gn_gamma, const float* __restrict__ gn_beta,
    const unsigned short* __restrict__ WnTh, const unsigned short* __restrict__ WnTl,
    const float* __restrict__ bxy,
    unsigned short* __restrict__ packed, unsigned short* __restrict__ xrArr,
    const int* __restrict__ esrc, const int* __restrict__ edst,
    const float* __restrict__ pos, int* __restrict__ cursor,
    nf4* __restrict__ meta, int E) {
  int bid = blockIdx.x;
  if (bid >= 256) {                        // ---- scatter part ----
    int e = (bid - 256) * 256 + threadIdx.x;
    if (e >= E) return;
    int src = esrc[e], dst = edst[e];
    int p = atomicAdd(&cursor[dst], 1);
    float2 ps = *(const float2*)(pos + 2 * src);
    float2 pd = *(const float2*)(pos + 2 * dst);
    float dx = ps.x - pd.x, dy = ps.y - pd.y;
    float d2 = fmaxf(dx * dx + dy * dy, 1e-8f);
    nf4 v = {__int_as_float(src), -dy / d2, dx / d2, 0.0f};
    meta[p] = v;
    return;
  }
  // ---- nodeP part: GN+modulate inline A-build + dual-output node GEMM ----
  int tid = threadIdx.x, wave = tid >> 6, lane = tid & 63;
  int m = lane & 15, q = lane >> 4;
  int r0 = bid * 128 + wave * 32;
  BF8 Ah[2][4], Al[2][4];
#pragma unroll
  for (int set = 0; set < 2; ++set) {
    int r = r0 + set * 16 + m;
    const float* hrow = h_source + (size_t)r * 128;
    const float* srow = style + (size_t)r * 256;
#pragma unroll
    for (int kc = 0; kc < 4; ++kc) {
      int ch = q * 8 + kc * 32;
      float4 x0 = *(const float4*)(hrow + ch);
      float4 x1 = *(const float4*)(hrow + ch + 4);
      float xs[8] = {x0.x, x0.y, x0.z, x0.w, x1.x, x1.y, x1.z, x1.w};
      float s8 = 0.f, q8 = 0.f;
#pragma unroll
      for (int j = 0; j < 8; ++j) { s8 += xs[j]; q8 += xs[j] * xs[j]; }
      float s16 = s8 + __shfl_xor(s8, 16);
      float q16 = q8 + __shfl_xor(q8, 16);
      float mu = s16 * (1.0f / 16.0f);
      float var = q16 * (1.0f / 16.0f) - mu * mu;
      float rv = rsqrtf(var + 1e-5f);
      float4 g0 = *(const float4*)(gn_gamma + ch);
      float4 g1 = *(const float4*)(gn_gamma + ch + 4);
      float4 be0 = *(const float4*)(gn_beta + ch);
      float4 be1 = *(const float4*)(gn_beta + ch + 4);
      float4 sg0 = *(const float4*)(srow + ch);
      float4 sg1 = *(const float4*)(srow + ch + 4);
      float4 sb0 = *(const float4*)(srow + 128 + ch);
      float4 sb1 = *(const float4*)(srow + 128 + ch + 4);
      float gg[8] = {g0.x, g0.y, g0.z, g0.w, g1.x, g1.y, g1.z, g1.w};
      float bb[8] = {be0.x, be0.y, be0.z, be0.w, be1.x, be1.y, be1.z, be1.w};
      float sg[8] = {sg0.x, sg0.y, sg0.z, sg0.w, sg1.x, sg1.y, sg1.z, sg1.w};
      float sb[8] = {sb0.x, sb0.y, sb0.z, sb0.w, sb1.x, sb1.y, sb1.z, sb1.w};
#pragma unroll
      for (int j = 0; j < 8; ++j) {
        float v = ((xs[j] - mu) * rv * gg[j] + bb[j]) * (1.0f + sg[j]) + sb[j];
        unsigned short h = f2bf(v);
        Ah[set][kc].s[j] = h;
        Al[set][kc].s[j] = f2bf(v - bf2f(h));
      }
    }
  }
  for (int nt = 0; nt < 32; ++nt) {
    f32x4 acc0 = {0.f, 0.f, 0.f, 0.f};
    f32x4 acc1 = {0.f, 0.f, 0.f, 0.f};
    const unsigned short* wr = WnTh + (size_t)(nt * 16 + m) * 128 + q * 8;
    if (nt < 16) {
#pragma unroll
      for (int kc = 0; kc < 4; ++kc) {
        BF8 bh; bh.u = *(const uint4*)(wr + kc * 32);
        acc0 = __builtin_amdgcn_mfma_f32_16x16x32_bf16(Ah[0][kc].v, bh.v, acc0, 0, 0, 0);
        acc1 = __builtin_amdgcn_mfma_f32_16x16x32_bf16(Ah[1][kc].v, bh.v, acc1, 0, 0, 0);
      }
    } else {
      const unsigned short* wl = WnTl + (size_t)((nt - 16) * 16 + m) * 128 + q * 8;
#pragma unroll
      for (int kc = 0; kc < 4; ++kc) {
        BF8 bh, blo;
        bh.u  = *(const uint4*)(wr + kc * 32);
        blo.u = *(const uint4*)(wl + kc * 32);
        acc0 = __builtin_amdgcn_mfma_f32_16x16x32_bf16(Ah[0][kc].v, bh.v, acc0, 0, 0, 0);
        acc0 = __builtin_amdgcn_mfma_f32_16x16x32_bf16(Al[0][kc].v, bh.v, acc0, 0, 0, 0);
        acc0 = __builtin_amdgcn_mfma_f32_16x16x32_bf16(Ah[0][kc].v, blo.v, acc0, 0, 0, 0);
        acc1 = __builtin_amdgcn_mfma_f32_16x16x32_bf16(Ah[1][kc].v, bh.v, acc1, 0, 0, 0);
        acc1 = __builtin_amdgcn_mfma_f32_16x16x32_bf16(Al[1][kc].v, bh.v, acc1, 0, 0, 0);
        acc1 = __builtin_amdgcn_mfma_f32_16x16x32_bf16(Ah[1][kc].v, blo.v, acc1, 0, 0, 0);
      }
    }
    int n = nt * 16 + m;
    float bv = (nt < 16) ? bxy[n] : 0.0f;
    // destination index inside interleaved packed row (-1 => xrArr)
    int pidx;
    if (nt < 8) {
      pidx = 6 * (n >> 1) + (n & 1);                       // xl slot
    } else if (nt >= 16) {
      int t = n - 256;                                     // 0..255: A then B
      int c = t & 127;
      pidx = 6 * (c >> 1) + ((t < 128) ? 2 : 4) + (c & 1); // A / B slot
    } else {
      pidx = -1;                                           // xr
    }
#pragma unroll
    for (int set = 0; set < 2; ++set) {
      f32x4 a = set ? acc1 : acc0;
#pragma unroll
      for (int i = 0; i < 4; ++i) {
        int row = r0 + set * 16 + q * 4 + i;
        unsigned short h = f2bf(a[i] + bv);
        if (pidx >= 0) packed[(size_t)row * 384 + pidx] = h;
        else           xrArr[(size_t)row * 128 + (n - 128)] = h;
      }
    }
  }
}

// ================= K4: fused edge pass =================
// 16-lane-group sum via DPP (quad_perm ^1, ^2, row_half_mirror, row_mirror):
// stays within each 16-lane row, no LDS/ds_swizzle.
__device__ __forceinline__ float dpp_red16(float p) {
  p += __int_as_float(__builtin_amdgcn_mov_dpp(__float_as_int(p), 0xB1, 0xF, 0xF, true));
  p += __int_as_float(__builtin_amdgcn_mov_dpp(__float_as_int(p), 0x4E, 0xF, 0xF, true));
  p += __int_as_float(__builtin_amdgcn_mov_dpp(__float_as_int(p), 0x141, 0xF, 0xF, true));
  p += __int_as_float(__builtin_amdgcn_mov_dpp(__float_as_int(p), 0x140, 0xF, 0xF, true));
  return p;
}

__device__ __forceinline__ void edge_compute(nf4 mt, U3 r, v2f xr, v2f Ad, v2f Bd,
                                             float a0, float a1,
                                             float& m, float& l, v2f& s) {
  v2f xl = bfpair(r.a);
  v2f A  = bfpair(r.b);
  v2f B  = bfpair(r.c);
  v2f z = xl + xr;
  z = (A - Ad) * mt.y + z;                 // v_pk_add(neg) + v_pk_fma
  z = (B - Bd) * mt.z + z;
  v2f zq = z * 0.2f;                       // leaky = max(z, 0.2z)
  float p = fmaf(a0, fmaxf(z.x, zq.x), a1 * fmaxf(z.y, zq.y));
  p = dpp_red16(p);
  // defer-max (THR=8): ex <= e^8, rescale branch ~once per node.
  if (__builtin_expect(p <= m + 8.0f, 1)) {
    float ex = __expf(p - m);
    l += ex;
    s = xl * ex + s;
  } else {                                 // first iter: m=-inf -> sc=0
    float sc = __expf(m - p);
    l = fmaf(l, sc, 1.0f);
    s = s * sc + xl;
    m = p;
  }
}

__global__ __launch_bounds__(256) void k_edge(const int* __restrict__ rowptr,
                                              const nf4* __restrict__ meta,
                                              const unsigned short* __restrict__ packed,
                                              const unsigned short* __restrict__ xrArr,
                                              const float* __restrict__ att,
                                              float* __restrict__ aggr, int N) {
  int tid = threadIdx.x;
  int d = blockIdx.x * 4 + (tid >> 6);
  if (d >= N) return;
  int lane = tid & 63;
  int c0 = lane * 2;
  unsigned lane12 = (unsigned)lane * 12u;
  float2 av = *(const float2*)(att + c0);
  const char* rbase = (const char*)packed;   // 768 B per row, lane's triple at +lane*12
  v2f xr;
  { float x, y; ld2bf(xrArr + (size_t)d * 128 + c0, x, y); xr.x = x; xr.y = y; }
  U3 rd = *(const U3*)(rbase + (unsigned)d * 768u + lane12);
  v2f Ad = bfpair(rd.b), Bd = bfpair(rd.c);
  int beg = rowptr[d], end = rowptr[d + 1];
  float m1 = -INFINITY, l1 = 0.f; v2f s1 = {0.f, 0.f};
  float m2 = -INFINITY, l2 = 0.f; v2f s2 = {0.f, 0.f};
  int j = beg, rem = end - beg;
  // software pipeline: meta 2 pairs ahead, rows 1 pair ahead.
  nf4 ma0 = {}, ma1 = {}, mb0 = {}, mb1 = {};
  U3 ra0 = {}, ra1 = {};
  if (rem >= 2) {
    ma0 = meta[j]; ma1 = meta[j + 1];
    ra0 = *(const U3*)(rbase + (unsigned)__float_as_int(ma0.x) * 768u + lane12);
    ra1 = *(const U3*)(rbase + (unsigned)__float_as_int(ma1.x) * 768u + lane12);
    if (rem >= 4) { mb0 = meta[j + 2]; mb1 = meta[j + 3]; }
  }
  for (; j + 5 < end; j += 2) {
    nf4 mc0 = meta[j + 4], mc1 = meta[j + 5];
    U3 rb0 = *(const U3*)(rbase + (unsigned)__float_as_int(mb0.x) * 768u + lane12);
    U3 rb1 = *(const U3*)(rbase + (unsigned)__float_as_int(mb1.x) * 768u + lane12);
    edge_compute(ma0, ra0, xr, Ad, Bd, av.x, av.y, m1, l1, s1);
    edge_compute(ma1, ra1, xr, Ad, Bd, av.x, av.y, m2, l2, s2);
    ma0 = mb0; ma1 = mb1; mb0 = mc0; mb1 = mc1;
    ra0 = rb0; ra1 = rb1;
  }
  rem = end - j;
  if (rem >= 4) {                           // rem in {4,5}
    U3 rb0 = *(const U3*)(rbase + (unsigned)__float_as_int(mb0.x) * 768u + lane12);
    U3 rb1 = *(const U3*)(rbase + (unsigned)__float_as_int(mb1.x) * 768u + lane12);
    edge_compute(ma0, ra0, xr, Ad, Bd, av.x, av.y, m1, l1, s1);
    edge_compute(ma1, ra1, xr, Ad, Bd, av.x, av.y, m2, l2, s2);
    edge_compute(mb0, rb0, xr, Ad, Bd, av.x, av.y, m1, l1, s1);
    edge_compute(mb1, rb1, xr, Ad, Bd, av.x, av.y, m2, l2, s2);
    if (rem == 5) {
      nf4 mt = meta[j + 4];
      U3 r = *(const U3*)(rbase + (unsigned)__float_as_int(mt.x) * 768u + lane12);
      edge_compute(mt, r, xr, Ad, Bd, av.x, av.y, m1, l1, s1);
    }
  } else if (rem >= 2) {                    // rem in {2,3}
    edge_compute(ma0, ra0, xr, Ad, Bd, av.x, av.y, m1, l1, s1);
    edge_compute(ma1, ra1, xr, Ad, Bd, av.x, av.y, m2, l2, s2);
    if (rem == 3) {
      nf4 mt = meta[j + 2];
      U3 r = *(const U3*)(rbase + (unsigned)__float_as_int(mt.x) * 768u + lane12);
      edge_compute(mt, r, xr, Ad, Bd, av.x, av.y, m1, l1, s1);
    }
  } else if (rem == 1) {
    nf4 mt = meta[j];
    U3 r = *(const U3*)(rbase + (unsigned)__float_as_int(mt.x) * 768u + lane12);
    edge_compute(mt, r, xr, Ad, Bd, av.x, av.y, m1, l1, s1);
  }
  float nm = fmaxf(m1, m2);
  float sc1 = (m1 == nm) ? 1.0f : __expf(m1 - nm);
  float sc2 = (m2 == nm) ? 1.0f : __expf(m2 - nm);
  float l = fmaf(l1, sc1, l2 * sc2);
  v2f o = s1 * sc1 + s2 * sc2;
  float inv = 1.0f / (l + 1e-16f);
  *(float2*)&aggr[(size_t)d * 128 + c0] = make_float2(o.x * inv, o.y * inv);
}

// ================= K5: fused MLP tail =================
__global__ __launch_bounds__(256) void k_mlp(const float* __restrict__ aggr,
                                             const unsigned short* __restrict__ WpT,
                                             const unsigned short* __restrict__ W1T,
                                             const unsigned short* __restrict__ W2T,
                                             const float* __restrict__ bpost2,
                                             const float* __restrict__ b1,
                                             const float* __restrict__ b2,
                                             const float* __restrict__ ln_g,
                                             const float* __restrict__ ln_b,
                                             const float* __restrict__ h_target,
                                             float* __restrict__ out) {
  __shared__ unsigned short Tb[64 * 136];
  __shared__ unsigned short Ub[64 * 136];
  int tid = threadIdx.x, wave = tid >> 6, lane = tid & 63;
  int m = lane & 15, q = lane >> 4;
  int r0 = blockIdx.x * 64 + wave * 16;
  int rb0 = wave * 16;
  BF8 Af[4];
  {
    const float* arow = aggr + (size_t)(r0 + m) * 128 + q * 8;
#pragma unroll
    for (int kc = 0; kc < 4; ++kc) {
      float4 x0 = *(const float4*)(arow + kc * 32);
      float4 x1 = *(const float4*)(arow + kc * 32 + 4);
      float xs[8] = {x0.x, x0.y, x0.z, x0.w, x1.x, x1.y, x1.z, x1.w};
#pragma unroll
      for (int jj = 0; jj < 8; ++jj) Af[kc].s[jj] = f2bf(xs[jj]);
    }
  }
  f32x4 acc[8];
#pragma unroll
  for (int t = 0; t < 8; ++t) {
    const unsigned short* wr = WpT + (size_t)(t * 16 + m) * 128 + q * 8;
    f32x4 a = {0.f, 0.f, 0.f, 0.f};
#pragma unroll
    for (int kc = 0; kc < 4; ++kc) {
      BF8 bh; bh.u = *(const uint4*)(wr + kc * 32);
      a = __builtin_amdgcn_mfma_f32_16x16x32_bf16(Af[kc].v, bh.v, a, 0, 0, 0);
    }
    acc[t] = a;
  }
  float sum[4] = {0, 0, 0, 0}, sq[4] = {0, 0, 0, 0};
#pragma unroll
  for (int t = 0; t < 8; ++t) {
    float bv = bpost2[t * 16 + m];
#pragma unroll
    for (int i = 0; i < 4; ++i) {
      float v = acc[t][i] + bv;
      acc[t][i] = v;
      sum[i] += v;
      sq[i] += v * v;
    }
  }
#pragma unroll
  for (int i = 0; i < 4; ++i) {
#pragma unroll
    for (int w = 1; w <= 8; w <<= 1) {
      sum[i] += __shfl_xor(sum[i], w);
      sq[i] += __shfl_xor(sq[i], w);
    }
  }
  float mu[4], rv[4];
#pragma unroll
  for (int i = 0; i < 4; ++i) {
    mu[i] = sum[i] * (1.0f / 128.0f);
    float var = sq[i] * (1.0f / 128.0f) - mu[i] * mu[i];
    rv[i] = rsqrtf(var + 1e-5f);
  }
#pragma unroll
  for (int t = 0; t < 8; ++t) {
    int n = t * 16 + m;
    float g = ln_g[n], b = ln_b[n];
#pragma unroll
    for (int i = 0; i < 4; ++i) {
      float v = (acc[t][i] - mu[i]) * rv[i] * g + b;
      Tb[(rb0 + q * 4 + i) * 136 + n] = f2bf(v);
    }
  }
  __syncthreads();
  BF8 Bf[4];
  {
    const unsigned short* tp = Tb + (rb0 + m) * 136 + q * 8;
#pragma unroll
    for (int kc = 0; kc < 4; ++kc) Bf[kc].u = *(const uint4*)(tp + kc * 32);
  }
#pragma unroll
  for (int t = 0; t < 8; ++t) {
    const unsigned short* wr = W1T + (size_t)(t * 16 + m) * 128 + q * 8;
    f32x4 a = {0.f, 0.f, 0.f, 0.f};
#pragma unroll
    for (int kc = 0; kc < 4; ++kc) {
      BF8 bh; bh.u = *(const uint4*)(wr + kc * 32);
      a = __builtin_amdgcn_mfma_f32_16x16x32_bf16(Bf[kc].v, bh.v, a, 0, 0, 0);
    }
    acc[t] = a;
  }
#pragma unroll
  for (int t = 0; t < 8; ++t) {
    int n = t * 16 + m;
    float bv = b1[n];
#pragma unroll
    for (int i = 0; i < 4; ++i) {
      float v = acc[t][i] + bv;
      v = 0.5f * v * (1.0f + erff(v * 0.70710678118654752f));
      Ub[(rb0 + q * 4 + i) * 136 + n] = f2bf(v);
    }
  }
  __syncthreads();
  BF8 Cf[4];
  {
    const unsigned short* up = Ub + (rb0 + m) * 136 + q * 8;
#pragma unroll
    for (int kc = 0; kc < 4; ++kc) Cf[kc].u = *(const uint4*)(up + kc * 32);
  }
#pragma unroll
  for (int t = 0; t < 8; ++t) {
    const unsigned short* wr = W2T + (size_t)(t * 16 + m) * 128 + q * 8;
    f32x4 a = {0.f, 0.f, 0.f, 0.f};
#pragma unroll
    for (int kc = 0; kc < 4; ++kc) {
      BF8 bh; bh.u = *(const uint4*)(wr + kc * 32);
      a = __builtin_amdgcn_mfma_f32_16x16x32_bf16(Cf[kc].v, bh.v, a, 0, 0, 0);
    }
    int n = t * 16 + m;
    float bv = b2[n];
#pragma unroll
    for (int i = 0; i < 4; ++i) {
      size_t off = (size_t)(r0 + q * 4 + i) * 128 + n;
      out[off] = a[i] + bv + h_target[off];
    }
  }
}

extern "C" void kernel_launch(void* const* d_in, const int* in_sizes, int n_in,
                              void* d_out, int out_size, void* d_ws, size_t ws_size,
                              hipStream_t stream) {
  const float* h_target = (const float*)d_in[0];
  const float* h_source = (const float*)d_in[1];
  const float* pos      = (const float*)d_in[2];
  const float* t_emb    = (const float*)d_in[3];
  const int*   eidx     = (const int*)d_in[4];
  const float* gn_gamma = (const float*)d_in[5];
  const float* gn_beta  = (const float*)d_in[6];
  const float* fc_W     = (const float*)d_in[7];
  const float* fc_b     = (const float*)d_in[8];
  const float* Wl       = (const float*)d_in[9];
  const float* bl       = (const float*)d_in[10];
  const float* Wr       = (const float*)d_in[11];
  const float* br       = (const float*)d_in[12];
  const float* We       = (const float*)d_in[13];
  const float* att      = (const float*)d_in[14];
  const float* gat_bias = (const float*)d_in[15];
  const float* Wpost    = (const float*)d_in[16];
  const float* bpost    = (const float*)d_in[17];
  const float* ln_g     = (const float*)d_in[18];
  const float* ln_b     = (const float*)d_in[19];
  const float* W1       = (const float*)d_in[20];
  const float* b1       = (const float*)d_in[21];
  const float* W2       = (const float*)d_in[22];
  const float* b2       = (const float*)d_in[23];

  const int N = in_sizes[0] / HID;     // 32768
  const int E = in_sizes[4] / 2;       // 524288
  const int* esrc = eidx;
  const int* edst = eidx + E;

  // ---- workspace (float offsets; MF = 1M floats = 4MB) ----
  float* ws = (float*)d_ws;
  const size_t MF = 1024 * 1024;
  float* style  = ws;                              // [0,8MF) fp32, dead after K3
  float* aggr   = ws;                              // [0,4MF) after k_edge
  unsigned short* packed = (unsigned short*)(ws + 8 * MF);   // [N][384] bf16 (interleaved)
  unsigned short* xrArr  = (unsigned short*)(ws + 14 * MF);  // [N][128] bf16
  nf4*   meta   = (nf4*)(ws + 16 * MF);            // [E]
  int*   rowptr = (int*)(ws + 18 * MF);
  int*   count  = rowptr + 32832;
  int*   cursor = count + 32832;
  unsigned short* wgt = (unsigned short*)(ws + 18 * MF + 131072);
  unsigned short* fcTh = wgt;
  unsigned short* fcTl = wgt + 32768;
  unsigned short* WnTh = wgt + 65536;
  unsigned short* WnTl = wgt + 131072;
  unsigned short* WpT  = wgt + 163840;
  unsigned short* W1T  = wgt + 180224;
  unsigned short* W2T  = wgt + 196608;
  float* bxy    = (float*)(wgt + 212992);
  float* bpost2 = bxy + 256;
  const size_t needed = (size_t)(18 * MF + 131072 + 106496 + 512) * 4;
  if (ws_size < needed) return;  // visible failure (out stays poisoned)

  dim3 blk(256);
  const int histB = (E + 255) / 256;   // 2048

  (void)hipMemsetAsync(count, 0, (size_t)N * 4, stream);
  // K1: prep (578) + hist (2048)
  k1_prep_hist<<<578 + histB, blk, 0, stream>>>(
      fc_W, Wl, Wr, We, Wpost, W1, W2, bl, br, gat_bias, bpost,
      fcTh, fcTl, WnTh, WnTl, WpT, W1T, W2T, bxy, bpost2, edst, count, E);
  // K2: style GEMM (512) + scan (1)
  k2_style_scan<<<513, blk, 0, stream>>>(t_emb, fcTh, fcTl, fc_b, style,
                                         count, rowptr, cursor, N, E);
  // K3: nodeP (256) + scatter (2048)
  k3_node_scatter<<<256 + histB, blk, 0, stream>>>(
      h_source, style, gn_gamma, gn_beta, WnTh, WnTl, bxy, packed, xrArr,
      esrc, edst, pos, cursor, meta, E);
  // K4: fused edge pass -> aggr (style region now dead)
  k_edge<<<(N + 3) / 4, blk, 0, stream>>>(rowptr, meta, packed, xrArr, att, aggr, N);
  // K5: fused MLP tail -> out
  k_mlp<<<N / 64, blk, 0, stream>>>(aggr, WpT, W1T, W2T, bpost2, b1, b2, ln_g, ln_b,
                                    h_target, (float*)d_out);
}

// Round 2
// 345.096 us; speedup vs baseline: 1.0563x; 1.0377x over previous
//
#include <hip/hip_runtime.h>
#include <hip/hip_bf16.h>
#include <math.h>

#define HID 128

typedef __bf16 bf16x8 __attribute__((ext_vector_type(8)));
typedef float f32x4 __attribute__((ext_vector_type(4)));
typedef float nf4 __attribute__((ext_vector_type(4)));
typedef float v2f __attribute__((ext_vector_type(2)));
union BF8 { uint4 u; bf16x8 v; unsigned short s[8]; };

struct __attribute__((packed, aligned(4))) U3 { unsigned a, b, c; };
// 12-byte edge meta: src node id, -dy/d2, dx/d2  (rank-placed, sorted by dst)
struct __attribute__((packed, aligned(4))) M3 { int s; float y, z; };

__device__ __forceinline__ unsigned short f2bf(float x) {
  unsigned u = __float_as_uint(x);
  unsigned r = u + 0x7FFFu + ((u >> 16) & 1u);   // RNE (finite inputs)
  return (unsigned short)(r >> 16);
}
__device__ __forceinline__ float bf2f(unsigned short h) {
  return __uint_as_float(((unsigned)h) << 16);
}
__device__ __forceinline__ void ld2bf(const unsigned short* p, float& x, float& y) {
  unsigned v = *(const unsigned*)p;
  x = __uint_as_float((v & 0xFFFFu) << 16);
  y = __uint_as_float(v & 0xFFFF0000u);
}
__device__ __forceinline__ v2f bfpair(unsigned w) {
  v2f r;
  r.x = __uint_as_float(w << 16);
  r.y = __uint_as_float(w & 0xFFFF0000u);
  return r;
}

// ================= K1: prep (blocks 0..577) + hist (blocks 578..) =================
// hist also persists each edge's within-dst rank (atomicAdd return value) so the
// K3 scatter needs no atomics at all.
__global__ __launch_bounds__(256) void k1_prep_hist(
    const float* __restrict__ fc_W, const float* __restrict__ Wl,
    const float* __restrict__ Wr, const float* __restrict__ We,
    const float* __restrict__ Wpost, const float* __restrict__ W1,
    const float* __restrict__ W2, const float* __restrict__ bl,
    const float* __restrict__ br, const float* __restrict__ gat_bias,
    const float* __restrict__ bpost,
    unsigned short* __restrict__ fcTh, unsigned short* __restrict__ fcTl,
    unsigned short* __restrict__ WnTh, unsigned short* __restrict__ WnTl,
    unsigned short* __restrict__ WpT, unsigned short* __restrict__ W1T,
    unsigned short* __restrict__ W2T,
    float* __restrict__ bxy, float* __restrict__ bpost2,
    const int* __restrict__ edst, int* __restrict__ count,
    int* __restrict__ rank, int E) {
  int bid = blockIdx.x;
  if (bid >= 578) {                        // ---- histogram + rank part ----
    int e = (bid - 578) * 256 + threadIdx.x;
    if (e < E) rank[e] = atomicAdd(&count[edst[e]], 1);
    return;
  }
  int gid = bid * 256 + threadIdx.x;
  if (gid < 32768) {                       // fc_W [128x256] -> fcT hi/lo [256][128]
    int n = gid >> 7, k = gid & 127;
    float x = fc_W[k * 256 + n];
    unsigned short h = f2bf(x);
    fcTh[n * 128 + k] = h;
    fcTl[n * 128 + k] = f2bf(x - bf2f(h));
  } else if (gid < 98304) {                // WnT [512][128] cols=[Wl|Wr|WeA|WeB]
    int i = gid - 32768; int n = i >> 7, k = i & 127;
    float x;
    if (n < 128)      x = Wl[k * 128 + n];
    else if (n < 256) x = Wr[k * 128 + (n - 128)];
    else if (n < 384) x = We[k * 128 + (n - 256)];
    else              x = We[(128 + k) * 128 + (n - 384)];
    unsigned short h = f2bf(x);
    WnTh[n * 128 + k] = h;
    if (n >= 256) WnTl[(n - 256) * 128 + k] = f2bf(x - bf2f(h));
  } else if (gid < 147456) {               // Wpost/W1/W2 -> T [128][128]
    int i = gid - 98304; int which = i >> 14; int j = i & 16383;
    int n = j >> 7, k = j & 127;
    const float* W = (which == 0) ? Wpost : (which == 1) ? W1 : W2;
    unsigned short* T = (which == 0) ? WpT : (which == 1) ? W1T : W2T;
    T[n * 128 + k] = f2bf(W[k * 128 + n]);
  } else if (gid < 147712) {               // bxy = [bl|br]
    int j = gid - 147456;
    bxy[j] = (j < 128) ? bl[j] : br[j - 128];
  } else if (gid < 147840) {               // bpost2 = bpost + gat_bias @ Wpost
    int t = gid - 147712;
    float s = bpost[t];
    for (int k = 0; k < 128; ++k) s += gat_bias[k] * Wpost[k * 128 + t];
    bpost2[t] = s;
  }
}

// ================= K2: style GEMM (blocks 0..511) + scan (block 512) =================
// style = t_emb @ fc_W + fc_b [N x 256], split hi/lo precision.
__global__ __launch_bounds__(256) void k2_style_scan(
    const float* __restrict__ A, const unsigned short* __restrict__ WTh,
    const unsigned short* __restrict__ WTl, const float* __restrict__ bias,
    float* __restrict__ C,
    const int* __restrict__ count, int* __restrict__ rowptr, int N, int E) {
  if (blockIdx.x == 512) {                 // ---- scan part (2-pass, 256 thr) ----
    __shared__ int wtot[4];
    int t = threadIdx.x, lane = t & 63, wv = t >> 6;
    const int4* c4 = (const int4*)count;
    int base = t * 32;
    int s = 0;
    for (int i = 0; i < 32; ++i) {
      int4 c = c4[base + i];
      s += c.x + c.y + c.z + c.w;
    }
    int incl = s;
#pragma unroll
    for (int off = 1; off < 64; off <<= 1) {
      int v = __shfl_up(incl, off);
      if (lane >= off) incl += v;
    }
    if (lane == 63) wtot[wv] = incl;
    __syncthreads();
    if (t == 0) {
      int a0 = wtot[0], a1 = wtot[1], a2 = wtot[2];
      wtot[0] = 0; wtot[1] = a0; wtot[2] = a0 + a1; wtot[3] = a0 + a1 + a2;
    }
    __syncthreads();
    int run = wtot[wv] + incl - s;
    for (int i = 0; i < 32; ++i) {
      int4 c = c4[base + i];
      int4 r;
      r.x = run; run += c.x;
      r.y = run; run += c.y;
      r.z = run; run += c.z;
      r.w = run; run += c.w;
      ((int4*)rowptr)[base + i] = r;
    }
    if (t == 255) rowptr[N] = E;
    return;
  }
  // ---- style GEMM part ----
  int tid = threadIdx.x;
  int wave = tid >> 6, lane = tid & 63;
  int m = lane & 15, q = lane >> 4;
  int r0 = blockIdx.x * 64 + wave * 16;
  const float* arow = A + (size_t)(r0 + m) * 128 + q * 8;
  BF8 Ah[4], Al[4];
#pragma unroll
  for (int kc = 0; kc < 4; ++kc) {
    float4 x0 = *(const float4*)(arow + kc * 32);
    float4 x1 = *(const float4*)(arow + kc * 32 + 4);
    float xs[8] = {x0.x, x0.y, x0.z, x0.w, x1.x, x1.y, x1.z, x1.w};
#pragma unroll
    for (int j = 0; j < 8; ++j) {
      unsigned short h = f2bf(xs[j]);
      Ah[kc].s[j] = h;
      Al[kc].s[j] = f2bf(xs[j] - bf2f(h));
    }
  }
  for (int nt = 0; nt < 16; ++nt) {
    const unsigned short* wr  = WTh + (size_t)(nt * 16 + m) * 128 + q * 8;
    const unsigned short* wrl = WTl + (size_t)(nt * 16 + m) * 128 + q * 8;
    f32x4 acc = {0.f, 0.f, 0.f, 0.f};
#pragma unroll
    for (int kc = 0; kc < 4; ++kc) {
      BF8 bh, blo;
      bh.u  = *(const uint4*)(wr + kc * 32);
      blo.u = *(const uint4*)(wrl + kc * 32);
      acc = __builtin_amdgcn_mfma_f32_16x16x32_bf16(Ah[kc].v, bh.v, acc, 0, 0, 0);
      acc = __builtin_amdgcn_mfma_f32_16x16x32_bf16(Al[kc].v, bh.v, acc, 0, 0, 0);
      acc = __builtin_amdgcn_mfma_f32_16x16x32_bf16(Ah[kc].v, blo.v, acc, 0, 0, 0);
    }
    int n = nt * 16 + m;
    float bv = bias[n];
#pragma unroll
    for (int i = 0; i < 4; ++i) {
      int row = r0 + q * 4 + i;
      C[(size_t)row * 256 + n] = acc[i] + bv;
    }
  }
}

// ================= K3: nodeP (blocks 0..255) + scatter (blocks 256..) =================
// packed row layout (interleaved for dwordx3 in k_edge): for channel pair c=0..63,
// ushort idx 6c..6c+5 = [xl_{2c}, xl_{2c+1}, A_{2c}, A_{2c+1}, B_{2c}, B_{2c+1}]
// scatter: atomic-free, p = rowptr[dst] + rank[e].
__global__ __launch_bounds__(256) void k3_node_scatter(
    const float* __restrict__ h_source, const float* __restrict__ style,
    const float* __restrict__ gn_gamma, const float* __restrict__ gn_beta,
    const unsigned short* __restrict__ WnTh, const unsigned short* __restrict__ WnTl,
    const float* __restrict__ bxy,
    unsigned short* __restrict__ packed, unsigned short* __restrict__ xrArr,
    const int* __restrict__ esrc, const int* __restrict__ edst,
    const float* __restrict__ pos, const int* __restrict__ rowptr,
    const int* __restrict__ rank, M3* __restrict__ meta, int E) {
  int bid = blockIdx.x;
  if (bid >= 256) {                        // ---- scatter part (no atomics) ----
    int e = (bid - 256) * 256 + threadIdx.x;
    if (e >= E) return;
    int src = esrc[e], dst = edst[e];
    int p = rowptr[dst] + rank[e];
    float2 ps = *(const float2*)(pos + 2 * src);
    float2 pd = *(const float2*)(pos + 2 * dst);
    float dx = ps.x - pd.x, dy = ps.y - pd.y;
    float d2 = fmaxf(dx * dx + dy * dy, 1e-8f);
    M3 v; v.s = src; v.y = -dy / d2; v.z = dx / d2;
    meta[p] = v;
    return;
  }
  // ---- nodeP part: GN+modulate inline A-build + dual-output node GEMM ----
  int tid = threadIdx.x, wave = tid >> 6, lane = tid & 63;
  int m = lane & 15, q = lane >> 4;
  int r0 = bid * 128 + wave * 32;
  BF8 Ah[2][4], Al[2][4];
#pragma unroll
  for (int set = 0; set < 2; ++set) {
    int r = r0 + set * 16 + m;
    const float* hrow = h_source + (size_t)r * 128;
    const float* srow = style + (size_t)r * 256;
#pragma unroll
    for (int kc = 0; kc < 4; ++kc) {
      int ch = q * 8 + kc * 32;
      float4 x0 = *(const float4*)(hrow + ch);
      float4 x1 = *(const float4*)(hrow + ch + 4);
      float xs[8] = {x0.x, x0.y, x0.z, x0.w, x1.x, x1.y, x1.z, x1.w};
      float s8 = 0.f, q8 = 0.f;
#pragma unroll
      for (int j = 0; j < 8; ++j) { s8 += xs[j]; q8 += xs[j] * xs[j]; }
      float s16 = s8 + __shfl_xor(s8, 16);
      float q16 = q8 + __shfl_xor(q8, 16);
      float mu = s16 * (1.0f / 16.0f);
      float var = q16 * (1.0f / 16.0f) - mu * mu;
      float rv = rsqrtf(var + 1e-5f);
      float4 g0 = *(const float4*)(gn_gamma + ch);
      float4 g1 = *(const float4*)(gn_gamma + ch + 4);
      float4 be0 = *(const float4*)(gn_beta + ch);
      float4 be1 = *(const float4*)(gn_beta + ch + 4);
      float4 sg0 = *(const float4*)(srow + ch);
      float4 sg1 = *(const float4*)(srow + ch + 4);
      float4 sb0 = *(const float4*)(srow + 128 + ch);
      float4 sb1 = *(const float4*)(srow + 128 + ch + 4);
      float gg[8] = {g0.x, g0.y, g0.z, g0.w, g1.x, g1.y, g1.z, g1.w};
      float bb[8] = {be0.x, be0.y, be0.z, be0.w, be1.x, be1.y, be1.z, be1.w};
      float sg[8] = {sg0.x, sg0.y, sg0.z, sg0.w, sg1.x, sg1.y, sg1.z, sg1.w};
      float sb[8] = {sb0.x, sb0.y, sb0.z, sb0.w, sb1.x, sb1.y, sb1.z, sb1.w};
#pragma unroll
      for (int j = 0; j < 8; ++j) {
        float v = ((xs[j] - mu) * rv * gg[j] + bb[j]) * (1.0f + sg[j]) + sb[j];
        unsigned short h = f2bf(v);
        Ah[set][kc].s[j] = h;
        Al[set][kc].s[j] = f2bf(v - bf2f(h));
      }
    }
  }
  for (int nt = 0; nt < 32; ++nt) {
    f32x4 acc0 = {0.f, 0.f, 0.f, 0.f};
    f32x4 acc1 = {0.f, 0.f, 0.f, 0.f};
    const unsigned short* wr = WnTh + (size_t)(nt * 16 + m) * 128 + q * 8;
    if (nt < 16) {
#pragma unroll
      for (int kc = 0; kc < 4; ++kc) {
        BF8 bh; bh.u = *(const uint4*)(wr + kc * 32);
        acc0 = __builtin_amdgcn_mfma_f32_16x16x32_bf16(Ah[0][kc].v, bh.v, acc0, 0, 0, 0);
        acc1 = __builtin_amdgcn_mfma_f32_16x16x32_bf16(Ah[1][kc].v, bh.v, acc1, 0, 0, 0);
      }
    } else {
      const unsigned short* wl = WnTl + (size_t)((nt - 16) * 16 + m) * 128 + q * 8;
#pragma unroll
      for (int kc = 0; kc < 4; ++kc) {
        BF8 bh, blo;
        bh.u  = *(const uint4*)(wr + kc * 32);
        blo.u = *(const uint4*)(wl + kc * 32);
        acc0 = __builtin_amdgcn_mfma_f32_16x16x32_bf16(Ah[0][kc].v, bh.v, acc0, 0, 0, 0);
        acc0 = __builtin_amdgcn_mfma_f32_16x16x32_bf16(Al[0][kc].v, bh.v, acc0, 0, 0, 0);
        acc0 = __builtin_amdgcn_mfma_f32_16x16x32_bf16(Ah[0][kc].v, blo.v, acc0, 0, 0, 0);
        acc1 = __builtin_amdgcn_mfma_f32_16x16x32_bf16(Ah[1][kc].v, bh.v, acc1, 0, 0, 0);
        acc1 = __builtin_amdgcn_mfma_f32_16x16x32_bf16(Al[1][kc].v, bh.v, acc1, 0, 0, 0);
        acc1 = __builtin_amdgcn_mfma_f32_16x16x32_bf16(Ah[1][kc].v, blo.v, acc1, 0, 0, 0);
      }
    }
    int n = nt * 16 + m;
    float bv = (nt < 16) ? bxy[n] : 0.0f;
    // destination index inside interleaved packed row (-1 => xrArr)
    int pidx;
    if (nt < 8) {
      pidx = 6 * (n >> 1) + (n & 1);                       // xl slot
    } else if (nt >= 16) {
      int t = n - 256;                                     // 0..255: A then B
      int c = t & 127;
      pidx = 6 * (c >> 1) + ((t < 128) ? 2 : 4) + (c & 1); // A / B slot
    } else {
      pidx = -1;                                           // xr
    }
#pragma unroll
    for (int set = 0; set < 2; ++set) {
      f32x4 a = set ? acc1 : acc0;
#pragma unroll
      for (int i = 0; i < 4; ++i) {
        int row = r0 + set * 16 + q * 4 + i;
        unsigned short h = f2bf(a[i] + bv);
        if (pidx >= 0) packed[(size_t)row * 384 + pidx] = h;
        else           xrArr[(size_t)row * 128 + (n - 128)] = h;
      }
    }
  }
}

// ================= K4: fused edge pass =================
// 16-lane-group sum via DPP (quad_perm ^1, ^2, row_half_mirror, row_mirror):
// stays within each 16-lane row, no LDS/ds_swizzle.
__device__ __forceinline__ float dpp_red16(float p) {
  p += __int_as_float(__builtin_amdgcn_mov_dpp(__float_as_int(p), 0xB1, 0xF, 0xF, true));
  p += __int_as_float(__builtin_amdgcn_mov_dpp(__float_as_int(p), 0x4E, 0xF, 0xF, true));
  p += __int_as_float(__builtin_amdgcn_mov_dpp(__float_as_int(p), 0x141, 0xF, 0xF, true));
  p += __int_as_float(__builtin_amdgcn_mov_dpp(__float_as_int(p), 0x140, 0xF, 0xF, true));
  return p;
}

__device__ __forceinline__ void edge_compute(M3 mt, U3 r, v2f xr, v2f Ad, v2f Bd,
                                             float a0, float a1,
                                             float& m, float& l, v2f& s) {
  v2f xl = bfpair(r.a);
  v2f A  = bfpair(r.b);
  v2f B  = bfpair(r.c);
  v2f z = xl + xr;
  z = (A - Ad) * mt.y + z;                 // v_pk_add(neg) + v_pk_fma
  z = (B - Bd) * mt.z + z;
  v2f zq = z * 0.2f;                       // leaky = max(z, 0.2z)
  float p = fmaf(a0, fmaxf(z.x, zq.x), a1 * fmaxf(z.y, zq.y));
  p = dpp_red16(p);
  // defer-max (THR=8): ex <= e^8, rescale branch ~once per node.
  if (__builtin_expect(p <= m + 8.0f, 1)) {
    float ex = __expf(p - m);
    l += ex;
    s = xl * ex + s;
  } else {                                 // first iter: m=-inf -> sc=0
    float sc = __expf(m - p);
    l = fmaf(l, sc, 1.0f);
    s = s * sc + xl;
    m = p;
  }
}

__global__ __launch_bounds__(256) void k_edge(const int* __restrict__ rowptr,
                                              const M3* __restrict__ meta,
                                              const unsigned short* __restrict__ packed,
                                              const unsigned short* __restrict__ xrArr,
                                              const float* __restrict__ att,
                                              float* __restrict__ aggr, int N) {
  int tid = threadIdx.x;
  int d = blockIdx.x * 4 + (tid >> 6);
  if (d >= N) return;
  int lane = tid & 63;
  int c0 = lane * 2;
  unsigned lane12 = (unsigned)lane * 12u;
  float2 av = *(const float2*)(att + c0);
  const char* rbase = (const char*)packed;   // 768 B per row, lane's triple at +lane*12
  v2f xr;
  { float x, y; ld2bf(xrArr + (size_t)d * 128 + c0, x, y); xr.x = x; xr.y = y; }
  U3 rd = *(const U3*)(rbase + (unsigned)d * 768u + lane12);
  v2f Ad = bfpair(rd.b), Bd = bfpair(rd.c);
  int beg = rowptr[d], end = rowptr[d + 1];
  float m1 = -INFINITY, l1 = 0.f; v2f s1 = {0.f, 0.f};
  float m2 = -INFINITY, l2 = 0.f; v2f s2 = {0.f, 0.f};
  int j = beg, rem = end - beg;
  // software pipeline: meta 2 pairs ahead, rows 1 pair ahead.
  M3 ma0 = {}, ma1 = {}, mb0 = {}, mb1 = {};
  U3 ra0 = {}, ra1 = {};
  if (rem >= 2) {
    ma0 = meta[j]; ma1 = meta[j + 1];
    ra0 = *(const U3*)(rbase + (unsigned)ma0.s * 768u + lane12);
    ra1 = *(const U3*)(rbase + (unsigned)ma1.s * 768u + lane12);
    if (rem >= 4) { mb0 = meta[j + 2]; mb1 = meta[j + 3]; }
  }
  for (; j + 5 < end; j += 2) {
    M3 mc0 = meta[j + 4], mc1 = meta[j + 5];
    U3 rb0 = *(const U3*)(rbase + (unsigned)mb0.s * 768u + lane12);
    U3 rb1 = *(const U3*)(rbase + (unsigned)mb1.s * 768u + lane12);
    edge_compute(ma0, ra0, xr, Ad, Bd, av.x, av.y, m1, l1, s1);
    edge_compute(ma1, ra1, xr, Ad, Bd, av.x, av.y, m2, l2, s2);
    ma0 = mb0; ma1 = mb1; mb0 = mc0; mb1 = mc1;
    ra0 = rb0; ra1 = rb1;
  }
  rem = end - j;
  if (rem >= 4) {                           // rem in {4,5}
    U3 rb0 = *(const U3*)(rbase + (unsigned)mb0.s * 768u + lane12);
    U3 rb1 = *(const U3*)(rbase + (unsigned)mb1.s * 768u + lane12);
    edge_compute(ma0, ra0, xr, Ad, Bd, av.x, av.y, m1, l1, s1);
    edge_compute(ma1, ra1, xr, Ad, Bd, av.x, av.y, m2, l2, s2);
    edge_compute(mb0, rb0, xr, Ad, Bd, av.x, av.y, m1, l1, s1);
    edge_compute(mb1, rb1, xr, Ad, Bd, av.x, av.y, m2, l2, s2);
    if (rem == 5) {
      M3 mt = meta[j + 4];
      U3 r = *(const U3*)(rbase + (unsigned)mt.s * 768u + lane12);
      edge_compute(mt, r, xr, Ad, Bd, av.x, av.y, m1, l1, s1);
    }
  } else if (rem >= 2) {                    // rem in {2,3}
    edge_compute(ma0, ra0, xr, Ad, Bd, av.x, av.y, m1, l1, s1);
    edge_compute(ma1, ra1, xr, Ad, Bd, av.x, av.y, m2, l2, s2);
    if (rem == 3) {
      M3 mt = meta[j + 2];
      U3 r = *(const U3*)(rbase + (unsigned)mt.s * 768u + lane12);
      edge_compute(mt, r, xr, Ad, Bd, av.x, av.y, m1, l1, s1);
    }
  } else if (rem == 1) {
    M3 mt = meta[j];
    U3 r = *(const U3*)(rbase + (unsigned)mt.s * 768u + lane12);
    edge_compute(mt, r, xr, Ad, Bd, av.x, av.y, m1, l1, s1);
  }
  float nm = fmaxf(m1, m2);
  float sc1 = (m1 == nm) ? 1.0f : __expf(m1 - nm);
  float sc2 = (m2 == nm) ? 1.0f : __expf(m2 - nm);
  float l = fmaf(l1, sc1, l2 * sc2);
  v2f o = s1 * sc1 + s2 * sc2;
  float inv = 1.0f / (l + 1e-16f);
  *(float2*)&aggr[(size_t)d * 128 + c0] = make_float2(o.x * inv, o.y * inv);
}

// ================= K5: fused MLP tail =================
__global__ __launch_bounds__(256) void k_mlp(const float* __restrict__ aggr,
                                             const unsigned short* __restrict__ WpT,
                                             const unsigned short* __restrict__ W1T,
                                             const unsigned short* __restrict__ W2T,
                                             const float* __restrict__ bpost2,
                                             const float* __restrict__ b1,
                                             const float* __restrict__ b2,
                                             const float* __restrict__ ln_g,
                                             const float* __restrict__ ln_b,
                                             const float* __restrict__ h_target,
                                             float* __restrict__ out) {
  __shared__ unsigned short Tb[64 * 136];
  __shared__ unsigned short Ub[64 * 136];
  int tid = threadIdx.x, wave = tid >> 6, lane = tid & 63;
  int m = lane & 15, q = lane >> 4;
  int r0 = blockIdx.x * 64 + wave * 16;
  int rb0 = wave * 16;
  BF8 Af[4];
  {
    const float* arow = aggr + (size_t)(r0 + m) * 128 + q * 8;
#pragma unroll
    for (int kc = 0; kc < 4; ++kc) {
      float4 x0 = *(const float4*)(arow + kc * 32);
      float4 x1 = *(const float4*)(arow + kc * 32 + 4);
      float xs[8] = {x0.x, x0.y, x0.z, x0.w, x1.x, x1.y, x1.z, x1.w};
#pragma unroll
      for (int jj = 0; jj < 8; ++jj) Af[kc].s[jj] = f2bf(xs[jj]);
    }
  }
  f32x4 acc[8];
#pragma unroll
  for (int t = 0; t < 8; ++t) {
    const unsigned short* wr = WpT + (size_t)(t * 16 + m) * 128 + q * 8;
    f32x4 a = {0.f, 0.f, 0.f, 0.f};
#pragma unroll
    for (int kc = 0; kc < 4; ++kc) {
      BF8 bh; bh.u = *(const uint4*)(wr + kc * 32);
      a = __builtin_amdgcn_mfma_f32_16x16x32_bf16(Af[kc].v, bh.v, a, 0, 0, 0);
    }
    acc[t] = a;
  }
  float sum[4] = {0, 0, 0, 0}, sq[4] = {0, 0, 0, 0};
#pragma unroll
  for (int t = 0; t < 8; ++t) {
    float bv = bpost2[t * 16 + m];
#pragma unroll
    for (int i = 0; i < 4; ++i) {
      float v = acc[t][i] + bv;
      acc[t][i] = v;
      sum[i] += v;
      sq[i] += v * v;
    }
  }
#pragma unroll
  for (int i = 0; i < 4; ++i) {
#pragma unroll
    for (int w = 1; w <= 8; w <<= 1) {
      sum[i] += __shfl_xor(sum[i], w);
      sq[i] += __shfl_xor(sq[i], w);
    }
  }
  float mu[4], rv[4];
#pragma unroll
  for (int i = 0; i < 4; ++i) {
    mu[i] = sum[i] * (1.0f / 128.0f);
    float var = sq[i] * (1.0f / 128.0f) - mu[i] * mu[i];
    rv[i] = rsqrtf(var + 1e-5f);
  }
#pragma unroll
  for (int t = 0; t < 8; ++t) {
    int n = t * 16 + m;
    float g = ln_g[n], b = ln_b[n];
#pragma unroll
    for (int i = 0; i < 4; ++i) {
      float v = (acc[t][i] - mu[i]) * rv[i] * g + b;
      Tb[(rb0 + q * 4 + i) * 136 + n] = f2bf(v);
    }
  }
  __syncthreads();
  BF8 Bf[4];
  {
    const unsigned short* tp = Tb + (rb0 + m) * 136 + q * 8;
#pragma unroll
    for (int kc = 0; kc < 4; ++kc) Bf[kc].u = *(const uint4*)(tp + kc * 32);
  }
#pragma unroll
  for (int t = 0; t < 8; ++t) {
    const unsigned short* wr = W1T + (size_t)(t * 16 + m) * 128 + q * 8;
    f32x4 a = {0.f, 0.f, 0.f, 0.f};
#pragma unroll
    for (int kc = 0; kc < 4; ++kc) {
      BF8 bh; bh.u = *(const uint4*)(wr + kc * 32);
      a = __builtin_amdgcn_mfma_f32_16x16x32_bf16(Bf[kc].v, bh.v, a, 0, 0, 0);
    }
    acc[t] = a;
  }
#pragma unroll
  for (int t = 0; t < 8; ++t) {
    int n = t * 16 + m;
    float bv = b1[n];
#pragma unroll
    for (int i = 0; i < 4; ++i) {
      float v = acc[t][i] + bv;
      v = 0.5f * v * (1.0f + erff(v * 0.70710678118654752f));
      Ub[(rb0 + q * 4 + i) * 136 + n] = f2bf(v);
    }
  }
  __syncthreads();
  BF8 Cf[4];
  {
    const unsigned short* up = Ub + (rb0 + m) * 136 + q * 8;
#pragma unroll
    for (int kc = 0; kc < 4; ++kc) Cf[kc].u = *(const uint4*)(up + kc * 32);
  }
#pragma unroll
  for (int t = 0; t < 8; ++t) {
    const unsigned short* wr = W2T + (size_t)(t * 16 + m) * 128 + q * 8;
    f32x4 a = {0.f, 0.f, 0.f, 0.f};
#pragma unroll
    for (int kc = 0; kc < 4; ++kc) {
      BF8 bh; bh.u = *(const uint4*)(wr + kc * 32);
      a = __builtin_amdgcn_mfma_f32_16x16x32_bf16(Cf[kc].v, bh.v, a, 0, 0, 0);
    }
    int n = t * 16 + m;
    float bv = b2[n];
#pragma unroll
    for (int i = 0; i < 4; ++i) {
      size_t off = (size_t)(r0 + q * 4 + i) * 128 + n;
      out[off] = a[i] + bv + h_target[off];
    }
  }
}

extern "C" void kernel_launch(void* const* d_in, const int* in_sizes, int n_in,
                              void* d_out, int out_size, void* d_ws, size_t ws_size,
                              hipStream_t stream) {
  const float* h_target = (const float*)d_in[0];
  const float* h_source = (const float*)d_in[1];
  const float* pos      = (const float*)d_in[2];
  const float* t_emb    = (const float*)d_in[3];
  const int*   eidx     = (const int*)d_in[4];
  const float* gn_gamma = (const float*)d_in[5];
  const float* gn_beta  = (const float*)d_in[6];
  const float* fc_W     = (const float*)d_in[7];
  const float* fc_b     = (const float*)d_in[8];
  const float* Wl       = (const float*)d_in[9];
  const float* bl       = (const float*)d_in[10];
  const float* Wr       = (const float*)d_in[11];
  const float* br       = (const float*)d_in[12];
  const float* We       = (const float*)d_in[13];
  const float* att      = (const float*)d_in[14];
  const float* gat_bias = (const float*)d_in[15];
  const float* Wpost    = (const float*)d_in[16];
  const float* bpost    = (const float*)d_in[17];
  const float* ln_g     = (const float*)d_in[18];
  const float* ln_b     = (const float*)d_in[19];
  const float* W1       = (const float*)d_in[20];
  const float* b1       = (const float*)d_in[21];
  const float* W2       = (const float*)d_in[22];
  const float* b2       = (const float*)d_in[23];

  const int N = in_sizes[0] / HID;     // 32768
  const int E = in_sizes[4] / 2;       // 524288
  const int* esrc = eidx;
  const int* edst = eidx + E;

  // ---- workspace (float offsets; MF = 1M floats = 4MB) ----
  float* ws = (float*)d_ws;
  const size_t MF = 1024 * 1024;
  float* style  = ws;                              // [0,8MF) fp32, dead after K3
  float* aggr   = ws;                              // [0,4MF) after k_edge
  unsigned short* packed = (unsigned short*)(ws + 8 * MF);   // [N][384] bf16 (interleaved)
  unsigned short* xrArr  = (unsigned short*)(ws + 14 * MF);  // [N][128] bf16
  // meta (12B x E = 6MB) + rank (4B x E = 2MB) exactly fill [16MF, 18MF)
  M3*  meta   = (M3*)(ws + 16 * MF);
  int* rank   = (int*)((char*)d_ws + 16 * MF * 4 + (size_t)524288 * 12);
  int* rowptr = (int*)(ws + 18 * MF);
  int* count  = rowptr + 32832;
  unsigned short* wgt = (unsigned short*)(ws + 18 * MF + 131072);
  unsigned short* fcTh = wgt;
  unsigned short* fcTl = wgt + 32768;
  unsigned short* WnTh = wgt + 65536;
  unsigned short* WnTl = wgt + 131072;
  unsigned short* WpT  = wgt + 163840;
  unsigned short* W1T  = wgt + 180224;
  unsigned short* W2T  = wgt + 196608;
  float* bxy    = (float*)(wgt + 212992);
  float* bpost2 = bxy + 256;
  const size_t needed = (size_t)(18 * MF + 131072 + 106496 + 512) * 4;
  if (ws_size < needed) return;  // visible failure (out stays poisoned)

  dim3 blk(256);
  const int histB = (E + 255) / 256;   // 2048

  (void)hipMemsetAsync(count, 0, (size_t)N * 4, stream);
  // K1: prep (578) + hist/rank (2048)
  k1_prep_hist<<<578 + histB, blk, 0, stream>>>(
      fc_W, Wl, Wr, We, Wpost, W1, W2, bl, br, gat_bias, bpost,
      fcTh, fcTl, WnTh, WnTl, WpT, W1T, W2T, bxy, bpost2, edst, count, rank, E);
  // K2: style GEMM (512) + scan (1)
  k2_style_scan<<<513, blk, 0, stream>>>(t_emb, fcTh, fcTl, fc_b, style,
                                         count, rowptr, N, E);
  // K3: nodeP (256) + scatter (2048, atomic-free)
  k3_node_scatter<<<256 + histB, blk, 0, stream>>>(
      h_source, style, gn_gamma, gn_beta, WnTh, WnTl, bxy, packed, xrArr,
      esrc, edst, pos, rowptr, rank, meta, E);
  // K4: fused edge pass -> aggr (style region now dead)
  k_edge<<<(N + 3) / 4, blk, 0, stream>>>(rowptr, meta, packed, xrArr, att, aggr, N);
  // K5: fused MLP tail -> out
  k_mlp<<<N / 64, blk, 0, stream>>>(aggr, WpT, W1T, W2T, bpost2, b1, b2, ln_g, ln_b,
                                    h_target, (float*)d_out);
}